// Round 6
// baseline (72.193 us; speedup 1.0000x reference)
//
#include <hip/hip_runtime.h>
#include <math.h>

#define NB 10
#define HH 100
#define TABN 2048
#define TAB_MAX 11.2f
#define INV_DELTA ((float)TABN / TAB_MAX)

// ---------------------------------------------------------------------------
// Sizes: B=8, N=64, C=64, H=100, R=10
// ws layout (floats):
//   tab     [2049][100]          = 204900   @ 0
//   M       [512 zb][6400 ho]    = 3276800  @ 204900
//   partial [8 z][64 b][64][64]  = 2097152  @ 3481700
//   s2      [8 z][16 ac][64]     = 8192     @ 5578852
//   cnt     [8] (uint)           = 8        @ 5587044
// 3 kernels (all wide), 2 boundaries.
// ---------------------------------------------------------------------------

// Fused: blocks 0..256 build the h2 lookup table; blocks 257..480 build M.
// Block 0 also zeroes the per-z completion counters used by kernel_redfinal.
__global__ __launch_bounds__(256) void tm_kernel(
    const float* __restrict__ in1, const float* __restrict__ in2,
    const float* __restrict__ w1, const float* __restrict__ w2,
    const float* __restrict__ w3,
    float* __restrict__ tab, float* __restrict__ Mout,
    unsigned int* __restrict__ cnt)
{
    __shared__ float s_w1[NB * HH];
    __shared__ float s_basis[8][NB];
    __shared__ float s_h1[8][HH];

    int tid = threadIdx.x;

    if (blockIdx.x == 0 && tid < 8) cnt[tid] = 0u;   // reset counters each call

    if (blockIdx.x < 257) {
        // ------------------- table path -------------------
        for (int i = tid; i < NB * HH; i += 256) s_w1[i] = w1[i];

        int p0 = blockIdx.x * 8;
        const float DELTA = TAB_MAX / (float)TABN;
        const float STEP = 10.0f / 9.0f;
        const float HALF_PI = 1.57079632679489662f;

        if (tid < 8 * NB) {
            int p = tid / NB, j = tid % NB;
            float r = (float)(p0 + p) * DELTA;
            float u = (r - (float)j * STEP) * (HALF_PI / STEP);
            float c = __cosf(u);
            s_basis[p][j] = (fabsf(u) < HALF_PI) ? c * c : 0.0f;
        }
        __syncthreads();

        const float inv_sqrt10 = 0.31622776601683794f;
        for (int task = tid; task < 8 * HH; task += 256) {
            int p = task / HH, k = task % HH;
            float acc = 0.f;
            #pragma unroll
            for (int j = 0; j < NB; ++j) acc += s_basis[p][j] * s_w1[j * HH + k];
            acc *= inv_sqrt10;
            float sg = 1.0f / (1.0f + __expf(-acc));
            s_h1[p][k] = acc * sg;
        }
        __syncthreads();

        if (tid < 8 * 25) {
            int p = tid / 25, k2g = tid % 25;
            int idx = p0 + p;
            float4 acc = make_float4(0.f, 0.f, 0.f, 0.f);
            #pragma unroll 4
            for (int k = 0; k < HH; ++k) {
                float hv = s_h1[p][k];
                float4 wv = *(const float4*)(w2 + (size_t)k * HH + k2g * 4);
                acc.x += hv * wv.x; acc.y += hv * wv.y; acc.z += hv * wv.z; acc.w += hv * wv.w;
            }
            if (idx <= TABN) {
                float4 o; float a;
                a = acc.x * 0.1f; o.x = a / (1.0f + __expf(-a));
                a = acc.y * 0.1f; o.y = a / (1.0f + __expf(-a));
                a = acc.z * 0.1f; o.z = a / (1.0f + __expf(-a));
                a = acc.w * 0.1f; o.w = a / (1.0f + __expf(-a));
                *(float4*)(tab + (size_t)idx * HH + k2g * 4) = o;
            }
        }
    } else {
        // ------------------- M path -------------------
        // M[zb][h*64+o] = sum_i w3[h][o*64+i] * x[zb][i]
        int m = blockIdx.x - 257;          // 0..223
        int zbg = m / 7, yc = m % 7;       // 32 zb-groups of 16, 7 task-chunks

        const float* xp[16];
        #pragma unroll
        for (int l = 0; l < 16; ++l) {
            int zb = zbg * 16 + l, z = zb >> 6, b = zb & 63;
            xp[l] = (b < 32) ? (in1 + (size_t)(z * 32 + b) * 64)
                             : (in2 + (size_t)(z * 32 + (b - 32)) * 64);
        }
        int task = yc * 256 + tid;
        if (task < 1600) {
            int h = task >> 4, og = task & 15;
            const float* wbase = w3 + (size_t)h * 4096 + og * 256;

            float4 acc[16];
            #pragma unroll
            for (int l = 0; l < 16; ++l) acc[l] = make_float4(0.f, 0.f, 0.f, 0.f);

            #pragma unroll 2
            for (int i4 = 0; i4 < 16; ++i4) {
                float4 wa = *(const float4*)(wbase + i4 * 4);
                float4 wb = *(const float4*)(wbase + 64 + i4 * 4);
                float4 wc = *(const float4*)(wbase + 128 + i4 * 4);
                float4 wd = *(const float4*)(wbase + 192 + i4 * 4);
                #pragma unroll
                for (int l = 0; l < 16; ++l) {
                    float4 xv = *(const float4*)(xp[l] + i4 * 4);
                    acc[l].x += wa.x * xv.x + wa.y * xv.y + wa.z * xv.z + wa.w * xv.w;
                    acc[l].y += wb.x * xv.x + wb.y * xv.y + wb.z * xv.z + wb.w * xv.w;
                    acc[l].z += wc.x * xv.x + wc.y * xv.y + wc.z * xv.z + wc.w * xv.w;
                    acc[l].w += wd.x * xv.x + wd.y * xv.y + wd.z * xv.z + wd.w * xv.w;
                }
            }
            #pragma unroll
            for (int l = 0; l < 16; ++l) {
                int zb = zbg * 16 + l;
                *(float4*)(Mout + (size_t)zb * 6400 + h * 64 + og * 4) = acc[l];
            }
        }
    }
}

// Y partial per (z,b): 128 threads, out tile 64a x 64o, thread = 8a x 4o.
// 3 ds_read_b128 per 32 FMA -> VALU-bound. LDS 51.7KB -> 3 blocks/CU.
__global__ __launch_bounds__(128) void kernel_Y(
    const float* __restrict__ xyz1, const float* __restrict__ xyz2,
    const float* __restrict__ tab, const float* __restrict__ M,
    float* __restrict__ partial)
{
    __shared__ float s_M[6400];     // 25.6 KB
    __shared__ float s_h2T[6400];   // 25.6 KB, [c][a] swizzled
    __shared__ int   s_i0[64];
    __shared__ float s_f[64];

    const int b = blockIdx.x, z = blockIdx.y;
    const int tid = threadIdx.x;   // 0..127

    if (tid < 64) {
        int a = tid;
        const float* pa = (a < 32) ? (xyz1 + (size_t)(z * 32 + a) * 3)
                                   : (xyz2 + (size_t)(z * 32 + (a - 32)) * 3);
        const float* pb = (b < 32) ? (xyz1 + (size_t)(z * 32 + b) * 3)
                                   : (xyz2 + (size_t)(z * 32 + (b - 32)) * 3);
        float dx = pa[0] - pb[0], dy = pa[1] - pb[1], dz = pa[2] - pb[2];
        float r = sqrtf(dx * dx + dy * dy + dz * dz + 1e-12f);
        float t = r * INV_DELTA;
        int i0 = (int)t;
        i0 = (i0 < TABN - 1) ? i0 : (TABN - 1);
        float f = t - (float)i0;
        s_i0[a] = i0;
        s_f[a] = (f < 1.0f) ? f : 1.0f;
    }
    // stage M[h][o] for this (z,b)
    {
        const float4* Msrc = (const float4*)(M + (size_t)(z * 64 + b) * 6400);
        float4* sM4 = (float4*)s_M;
        for (int i = tid; i < 1600; i += 128) sM4[i] = Msrc[i];
    }
    __syncthreads();

    // lerp h2 transposed+swizzled; thread owns fixed a4 (tab rows L1-resident)
    {
        int a4 = tid >> 3;       // 0..15
        int cg2 = tid & 7;       // 0..7
        int i0a[4]; float fa[4];
        #pragma unroll
        for (int k = 0; k < 4; ++k) {
            i0a[k] = s_i0[a4 * 4 + k];
            fa[k]  = s_f[a4 * 4 + k];
        }
        for (int c = cg2; c < 100; c += 8) {
            float4 hv;
            #pragma unroll
            for (int k = 0; k < 4; ++k) {
                const float* tp = tab + (size_t)i0a[k] * HH + c;
                float v0 = tp[0], v1 = tp[HH];
                ((float*)&hv)[k] = fmaf(fa[k], v1 - v0, v0);
            }
            *(float4*)&s_h2T[c * 64 + ((a4 ^ (c & 7)) << 2)] = hv;
        }
    }
    __syncthreads();

    const int og = tid & 15;     // o = og*4 .. og*4+3
    const int ag = tid >> 4;     // a = ag*8 .. ag*8+7
    float4 acc[8];
    #pragma unroll
    for (int k = 0; k < 8; ++k) acc[k] = make_float4(0.f, 0.f, 0.f, 0.f);

    #pragma unroll 4
    for (int c = 0; c < 100; ++c) {
        float4 hv0 = *(const float4*)&s_h2T[c * 64 + (((2 * ag) ^ (c & 7)) << 2)];
        float4 hv1 = *(const float4*)&s_h2T[c * 64 + (((2 * ag + 1) ^ (c & 7)) << 2)];
        float4 mv = *(const float4*)&s_M[c * 64 + og * 4];
        acc[0].x += hv0.x * mv.x; acc[0].y += hv0.x * mv.y; acc[0].z += hv0.x * mv.z; acc[0].w += hv0.x * mv.w;
        acc[1].x += hv0.y * mv.x; acc[1].y += hv0.y * mv.y; acc[1].z += hv0.y * mv.z; acc[1].w += hv0.y * mv.w;
        acc[2].x += hv0.z * mv.x; acc[2].y += hv0.z * mv.y; acc[2].z += hv0.z * mv.z; acc[2].w += hv0.z * mv.w;
        acc[3].x += hv0.w * mv.x; acc[3].y += hv0.w * mv.y; acc[3].z += hv0.w * mv.z; acc[3].w += hv0.w * mv.w;
        acc[4].x += hv1.x * mv.x; acc[4].y += hv1.x * mv.y; acc[4].z += hv1.x * mv.z; acc[4].w += hv1.x * mv.w;
        acc[5].x += hv1.y * mv.x; acc[5].y += hv1.y * mv.y; acc[5].z += hv1.y * mv.z; acc[5].w += hv1.y * mv.w;
        acc[6].x += hv1.z * mv.x; acc[6].y += hv1.z * mv.y; acc[6].z += hv1.z * mv.z; acc[6].w += hv1.z * mv.w;
        acc[7].x += hv1.w * mv.x; acc[7].y += hv1.w * mv.y; acc[7].z += hv1.w * mv.z; acc[7].w += hv1.w * mv.w;
    }

    size_t base = ((size_t)(z * 64 + b) * 64 + ag * 8) * 64 + og * 4;
    #pragma unroll
    for (int k = 0; k < 8; ++k)
        *(float4*)&partial[base + (size_t)k * 64] = acc[k];
}

// redfinal: grid (8 z, 16 ac), 256 thr. Wide reduction over b, then the LAST
// block per z (device-scope counter) finalizes: normalize (ddof=1), fc3+leaky,
// fc2, sigmoid. Fully deterministic (fixed reduction orders).
__global__ __launch_bounds__(256) void kernel_redfinal(
    const float* __restrict__ partial, const int* __restrict__ mask,
    const float* __restrict__ fc3w, const float* __restrict__ fc2w,
    float* __restrict__ s2, unsigned int* __restrict__ cnt,
    float* __restrict__ out)
{
    __shared__ float sred[4][64];
    __shared__ float s_sn[64];
    __shared__ unsigned int s_old;

    const int z = blockIdx.x, ac = blockIdx.y;
    const int tid = threadIdx.x;
    const int o = tid & 63, ar = tid >> 6;
    const int a = ac * 4 + ar;

    float val = 0.f;
    #pragma unroll 8
    for (int b = 0; b < 64; ++b)
        val += partial[((size_t)(z * 64 + b) * 64 + a) * 64 + o];

    const float scale = 0.0125f;   // (1/sqrt(100)) * (1/sqrt(64))
    float m = (mask[z * 64 + a] != 0) ? scale : 0.0f;
    sred[ar][o] = fabsf(val) * m;
    __syncthreads();

    if (tid < 64) {
        float v = sred[0][o] + sred[1][o] + sred[2][o] + sred[3][o];
        __hip_atomic_store(&s2[((size_t)z * 16 + ac) * 64 + o], v,
                           __ATOMIC_RELEASE, __HIP_MEMORY_SCOPE_AGENT);
    }
    __syncthreads();

    if (tid == 0) {
        __threadfence();
        s_old = atomicAdd(&cnt[z], 1u);
    }
    __syncthreads();
    if (s_old != 15u) return;          // not the last block for this z

    // ---- last block: finalize ----
    if (tid < 64) {
        __threadfence();
        float s = 0.f;
        #pragma unroll
        for (int g = 0; g < 16; ++g)
            s += __hip_atomic_load(&s2[((size_t)z * 16 + g) * 64 + tid],
                                   __ATOMIC_ACQUIRE, __HIP_MEMORY_SCOPE_AGENT);

        float tot = s;
        #pragma unroll
        for (int d = 32; d >= 1; d >>= 1) tot += __shfl_xor(tot, d, 64);
        float mean = tot * (1.0f / 64.0f);
        float dv = s - mean;
        float v2 = dv * dv;
        #pragma unroll
        for (int d = 32; d >= 1; d >>= 1) v2 += __shfl_xor(v2, d, 64);
        float var = v2 * (1.0f / 63.0f);   // ddof=1
        s_sn[tid] = dv / (sqrtf(var) + 1e-6f);
    }
    __syncthreads();

    if (tid < 64) {
        float accf = 0.f;
        #pragma unroll 8
        for (int i = 0; i < 64; ++i) accf += s_sn[i] * fc3w[i * 64 + tid];
        accf *= 0.125f;                    // 1/sqrt(C)
        float t = (accf > 0.f) ? accf : 0.01f * accf;
        float pr = t * fc2w[tid];
        #pragma unroll
        for (int d = 32; d >= 1; d >>= 1) pr += __shfl_xor(pr, d, 64);
        if (tid == 0) out[z] = 1.0f / (1.0f + expf(-0.125f * pr));
    }
}

extern "C" void kernel_launch(void* const* d_in, const int* in_sizes, int n_in,
                              void* d_out, int out_size, void* d_ws, size_t ws_size,
                              hipStream_t stream) {
    const float* in1  = (const float*)d_in[0];
    const float* in2  = (const float*)d_in[1];
    const float* xyz1 = (const float*)d_in[2];
    const float* xyz2 = (const float*)d_in[3];
    const int*   mask = (const int*)d_in[4];
    const float* w1   = (const float*)d_in[5];
    const float* w2   = (const float*)d_in[6];
    const float* w3   = (const float*)d_in[7];
    const float* fc3w = (const float*)d_in[8];
    const float* fc2w = (const float*)d_in[9];
    float* out = (float*)d_out;

    float* ws      = (float*)d_ws;
    float* tab     = ws;                           // 204900
    float* Mg      = ws + 204900;                  // 3276800
    float* partial = ws + 3481700;                 // 2097152
    float* s2      = ws + 5578852;                 // 8192
    unsigned int* cnt = (unsigned int*)(ws + 5587044);  // 8

    tm_kernel<<<481, 256, 0, stream>>>(in1, in2, w1, w2, w3, tab, Mg, cnt);
    kernel_Y<<<dim3(64, 8), 128, 0, stream>>>(xyz1, xyz2, tab, Mg, partial);
    kernel_redfinal<<<dim3(8, 16), 256, 0, stream>>>(partial, mask, fc3w, fc2w,
                                                     s2, cnt, out);
}

// Round 7
// 61.381 us; speedup vs baseline: 1.1761x; 1.1761x over previous
//
#include <hip/hip_runtime.h>
#include <math.h>

#define NB 10
#define HH 100
#define TABN 2048
#define TAB_MAX 11.2f
#define INV_DELTA ((float)TABN / TAB_MAX)

// ---------------------------------------------------------------------------
// Sizes: B=8, N=64, C=64, H=100, R=10
// ws layout (floats):
//   tab     [2049][100]          = 204900   @ 0
//   M       [512 zb][6400 ho]    = 3276800  @ 204900
//   partial [8 z][64 b][64][64]  = 2097152  @ 3481700
//   s2      [8 z][16 ac][64]     = 8192     @ 5578852
//   cnt     [8] (uint)           = 8        @ 5587044
// 3 kernels (tm, Y, redfinal), 2 boundaries.
// R3-proven internals: LDS-staged x in tm's M path; 256-thread Y.
// ---------------------------------------------------------------------------

// Fused: blocks 0..256 build the h2 lookup table; blocks 257..480 build M.
// Block 0 also zeroes the per-z completion counters used by kernel_redfinal.
__global__ __launch_bounds__(256) void tm_kernel(
    const float* __restrict__ in1, const float* __restrict__ in2,
    const float* __restrict__ w1, const float* __restrict__ w2,
    const float* __restrict__ w3,
    float* __restrict__ tab, float* __restrict__ Mout,
    unsigned int* __restrict__ cnt)
{
    __shared__ float s_w1[NB * HH];
    __shared__ float s_basis[8][NB];
    __shared__ float s_h1[8][HH];
    __shared__ float s_x[16][64];

    int tid = threadIdx.x;

    if (blockIdx.x == 0 && tid < 8) cnt[tid] = 0u;   // reset counters each call

    if (blockIdx.x < 257) {
        // ------------------- table path -------------------
        for (int i = tid; i < NB * HH; i += 256) s_w1[i] = w1[i];

        int p0 = blockIdx.x * 8;
        const float DELTA = TAB_MAX / (float)TABN;
        const float STEP = 10.0f / 9.0f;
        const float HALF_PI = 1.57079632679489662f;

        if (tid < 8 * NB) {
            int p = tid / NB, j = tid % NB;
            float r = (float)(p0 + p) * DELTA;
            float u = (r - (float)j * STEP) * (HALF_PI / STEP);
            float c = __cosf(u);
            s_basis[p][j] = (fabsf(u) < HALF_PI) ? c * c : 0.0f;
        }
        __syncthreads();

        const float inv_sqrt10 = 0.31622776601683794f;
        for (int task = tid; task < 8 * HH; task += 256) {
            int p = task / HH, k = task % HH;
            float acc = 0.f;
            #pragma unroll
            for (int j = 0; j < NB; ++j) acc += s_basis[p][j] * s_w1[j * HH + k];
            acc *= inv_sqrt10;
            float sg = 1.0f / (1.0f + __expf(-acc));
            s_h1[p][k] = acc * sg;
        }
        __syncthreads();

        if (tid < 8 * 25) {
            int p = tid / 25, k2g = tid % 25;
            int idx = p0 + p;
            float4 acc = make_float4(0.f, 0.f, 0.f, 0.f);
            #pragma unroll 4
            for (int k = 0; k < HH; ++k) {
                float hv = s_h1[p][k];
                float4 wv = *(const float4*)(w2 + (size_t)k * HH + k2g * 4);
                acc.x += hv * wv.x; acc.y += hv * wv.y; acc.z += hv * wv.z; acc.w += hv * wv.w;
            }
            if (idx <= TABN) {
                float4 o; float a;
                a = acc.x * 0.1f; o.x = a / (1.0f + __expf(-a));
                a = acc.y * 0.1f; o.y = a / (1.0f + __expf(-a));
                a = acc.z * 0.1f; o.z = a / (1.0f + __expf(-a));
                a = acc.w * 0.1f; o.w = a / (1.0f + __expf(-a));
                *(float4*)(tab + (size_t)idx * HH + k2g * 4) = o;
            }
        }
    } else {
        // ------------------- M path (LDS-staged x, R3 form) -------------------
        // M[zb][h*64+o] = sum_i w3[h][o*64+i] * x[zb][i]
        int m = blockIdx.x - 257;          // 0..223
        int zbg = m / 7, yc = m % 7;       // 32 zb-groups of 16, 7 task-chunks

        {
            int lz = tid >> 4, q = tid & 15;
            int zb = zbg * 16 + lz;
            int z = zb >> 6, b = zb & 63;
            const float* src = (b < 32) ? (in1 + (size_t)(z * 32 + b) * 64)
                                        : (in2 + (size_t)(z * 32 + (b - 32)) * 64);
            *(float4*)&s_x[lz][q * 4] = *(const float4*)(src + q * 4);
        }
        __syncthreads();

        int task = yc * 256 + tid;         // (h, og): 1600 tasks
        if (task < 1600) {
            int h = task >> 4, og = task & 15;
            const float* wbase = w3 + (size_t)h * 4096 + og * 256;

            float4 acc[16];
            #pragma unroll
            for (int l = 0; l < 16; ++l) acc[l] = make_float4(0.f, 0.f, 0.f, 0.f);

            const float4* sx4 = (const float4*)s_x;
            #pragma unroll 2
            for (int i4 = 0; i4 < 16; ++i4) {
                float4 wa = *(const float4*)(wbase + i4 * 4);
                float4 wb = *(const float4*)(wbase + 64 + i4 * 4);
                float4 wc = *(const float4*)(wbase + 128 + i4 * 4);
                float4 wd = *(const float4*)(wbase + 192 + i4 * 4);
                #pragma unroll
                for (int l = 0; l < 16; ++l) {
                    float4 xv = sx4[l * 16 + i4];
                    acc[l].x += wa.x * xv.x + wa.y * xv.y + wa.z * xv.z + wa.w * xv.w;
                    acc[l].y += wb.x * xv.x + wb.y * xv.y + wb.z * xv.z + wb.w * xv.w;
                    acc[l].z += wc.x * xv.x + wc.y * xv.y + wc.z * xv.z + wc.w * xv.w;
                    acc[l].w += wd.x * xv.x + wd.y * xv.y + wd.z * xv.z + wd.w * xv.w;
                }
            }
            #pragma unroll
            for (int l = 0; l < 16; ++l) {
                int zb = zbg * 16 + l;
                *(float4*)(Mout + (size_t)zb * 6400 + h * 64 + og * 4) = acc[l];
            }
        }
    }
}

// Y partial per (z,b): 256 threads (R3 form), out tile 64a x 64o,
// thread = 4a x 4o -> 2 ds_read_b128 per 16 FMA; 8 waves/CU resident.
__global__ __launch_bounds__(256) void kernel_Y(
    const float* __restrict__ xyz1, const float* __restrict__ xyz2,
    const float* __restrict__ tab, const float* __restrict__ M,
    float* __restrict__ partial)
{
    __shared__ float s_M[6400];     // 25.6 KB
    __shared__ float s_h2T[6400];   // 25.6 KB, [c][a] swizzled
    __shared__ int   s_i0[64];
    __shared__ float s_f[64];

    const int z = blockIdx.x, b = blockIdx.y;
    const int tid = threadIdx.x;   // 0..255

    if (tid < 64) {
        int a = tid;
        const float* pa = (a < 32) ? (xyz1 + (size_t)(z * 32 + a) * 3)
                                   : (xyz2 + (size_t)(z * 32 + (a - 32)) * 3);
        const float* pb = (b < 32) ? (xyz1 + (size_t)(z * 32 + b) * 3)
                                   : (xyz2 + (size_t)(z * 32 + (b - 32)) * 3);
        float dx = pa[0] - pb[0], dy = pa[1] - pb[1], dz = pa[2] - pb[2];
        float r = sqrtf(dx * dx + dy * dy + dz * dz + 1e-12f);
        float t = r * INV_DELTA;
        int i0 = (int)t;
        i0 = (i0 < TABN - 1) ? i0 : (TABN - 1);
        float f = t - (float)i0;
        s_i0[a] = i0;
        s_f[a] = (f < 1.0f) ? f : 1.0f;
    }
    // stage M[h][o] for this (z,b)
    {
        const float4* Msrc = (const float4*)(M + (size_t)(z * 64 + b) * 6400);
        float4* sM4 = (float4*)s_M;
        for (int i = tid; i < 1600; i += 256) sM4[i] = Msrc[i];
    }
    __syncthreads();

    // lerp h2 transposed+swizzled: task = (a4, c)
    for (int task = tid; task < 1600; task += 256) {
        int a4 = task / 100, c = task - a4 * 100;
        float4 hv;
        #pragma unroll
        for (int k = 0; k < 4; ++k) {
            int a = a4 * 4 + k;
            int i0 = s_i0[a];
            float f = s_f[a];
            const float* tp = tab + (size_t)i0 * HH + c;
            float v0 = tp[0], v1 = tp[HH];
            ((float*)&hv)[k] = fmaf(f, v1 - v0, v0);
        }
        *(float4*)&s_h2T[c * 64 + ((a4 ^ (c & 7)) << 2)] = hv;
    }
    __syncthreads();

    const int og = tid & 15, ag = tid >> 4;
    float4 acc0 = make_float4(0.f, 0.f, 0.f, 0.f);
    float4 acc1 = make_float4(0.f, 0.f, 0.f, 0.f);
    float4 acc2 = make_float4(0.f, 0.f, 0.f, 0.f);
    float4 acc3 = make_float4(0.f, 0.f, 0.f, 0.f);

    #pragma unroll 4
    for (int c = 0; c < 100; ++c) {
        float4 mv = *(const float4*)&s_M[c * 64 + og * 4];
        float4 hv = *(const float4*)&s_h2T[c * 64 + ((ag ^ (c & 7)) << 2)];
        acc0.x += hv.x * mv.x; acc0.y += hv.x * mv.y; acc0.z += hv.x * mv.z; acc0.w += hv.x * mv.w;
        acc1.x += hv.y * mv.x; acc1.y += hv.y * mv.y; acc1.z += hv.y * mv.z; acc1.w += hv.y * mv.w;
        acc2.x += hv.z * mv.x; acc2.y += hv.z * mv.y; acc2.z += hv.z * mv.z; acc2.w += hv.z * mv.w;
        acc3.x += hv.w * mv.x; acc3.y += hv.w * mv.y; acc3.z += hv.w * mv.z; acc3.w += hv.w * mv.w;
    }

    size_t base = ((size_t)(z * 64 + b) * 64 + ag * 4) * 64 + og * 4;
    *(float4*)&partial[base]       = acc0;
    *(float4*)&partial[base + 64]  = acc1;
    *(float4*)&partial[base + 128] = acc2;
    *(float4*)&partial[base + 192] = acc3;
}

// redfinal: grid (8 z, 16 ac), 256 thr. Wide reduction over b, then the LAST
// block per z (device-scope counter) finalizes: normalize (ddof=1), fc3+leaky,
// fc2, sigmoid. Fully deterministic (fixed reduction orders).
__global__ __launch_bounds__(256) void kernel_redfinal(
    const float* __restrict__ partial, const int* __restrict__ mask,
    const float* __restrict__ fc3w, const float* __restrict__ fc2w,
    float* __restrict__ s2, unsigned int* __restrict__ cnt,
    float* __restrict__ out)
{
    __shared__ float sred[4][64];
    __shared__ float s_sn[64];
    __shared__ unsigned int s_old;

    const int z = blockIdx.x, ac = blockIdx.y;
    const int tid = threadIdx.x;
    const int o = tid & 63, ar = tid >> 6;
    const int a = ac * 4 + ar;

    float val = 0.f;
    #pragma unroll 8
    for (int b = 0; b < 64; ++b)
        val += partial[((size_t)(z * 64 + b) * 64 + a) * 64 + o];

    const float scale = 0.0125f;   // (1/sqrt(100)) * (1/sqrt(64))
    float m = (mask[z * 64 + a] != 0) ? scale : 0.0f;
    sred[ar][o] = fabsf(val) * m;
    __syncthreads();

    if (tid < 64) {
        float v = sred[0][o] + sred[1][o] + sred[2][o] + sred[3][o];
        __hip_atomic_store(&s2[((size_t)z * 16 + ac) * 64 + o], v,
                           __ATOMIC_RELEASE, __HIP_MEMORY_SCOPE_AGENT);
    }
    __syncthreads();

    if (tid == 0) {
        __threadfence();
        s_old = atomicAdd(&cnt[z], 1u);
    }
    __syncthreads();
    if (s_old != 15u) return;          // not the last block for this z

    // ---- last block: finalize ----
    if (tid < 64) {
        __threadfence();
        float s = 0.f;
        #pragma unroll
        for (int g = 0; g < 16; ++g)
            s += __hip_atomic_load(&s2[((size_t)z * 16 + g) * 64 + tid],
                                   __ATOMIC_ACQUIRE, __HIP_MEMORY_SCOPE_AGENT);

        float tot = s;
        #pragma unroll
        for (int d = 32; d >= 1; d >>= 1) tot += __shfl_xor(tot, d, 64);
        float mean = tot * (1.0f / 64.0f);
        float dv = s - mean;
        float v2 = dv * dv;
        #pragma unroll
        for (int d = 32; d >= 1; d >>= 1) v2 += __shfl_xor(v2, d, 64);
        float var = v2 * (1.0f / 63.0f);   // ddof=1
        s_sn[tid] = dv / (sqrtf(var) + 1e-6f);
    }
    __syncthreads();

    if (tid < 64) {
        float accf = 0.f;
        #pragma unroll 8
        for (int i = 0; i < 64; ++i) accf += s_sn[i] * fc3w[i * 64 + tid];
        accf *= 0.125f;                    // 1/sqrt(C)
        float t = (accf > 0.f) ? accf : 0.01f * accf;
        float pr = t * fc2w[tid];
        #pragma unroll
        for (int d = 32; d >= 1; d >>= 1) pr += __shfl_xor(pr, d, 64);
        if (tid == 0) out[z] = 1.0f / (1.0f + expf(-0.125f * pr));
    }
}

extern "C" void kernel_launch(void* const* d_in, const int* in_sizes, int n_in,
                              void* d_out, int out_size, void* d_ws, size_t ws_size,
                              hipStream_t stream) {
    const float* in1  = (const float*)d_in[0];
    const float* in2  = (const float*)d_in[1];
    const float* xyz1 = (const float*)d_in[2];
    const float* xyz2 = (const float*)d_in[3];
    const int*   mask = (const int*)d_in[4];
    const float* w1   = (const float*)d_in[5];
    const float* w2   = (const float*)d_in[6];
    const float* w3   = (const float*)d_in[7];
    const float* fc3w = (const float*)d_in[8];
    const float* fc2w = (const float*)d_in[9];
    float* out = (float*)d_out;

    float* ws      = (float*)d_ws;
    float* tab     = ws;                           // 204900
    float* Mg      = ws + 204900;                  // 3276800
    float* partial = ws + 3481700;                 // 2097152
    float* s2      = ws + 5578852;                 // 8192
    unsigned int* cnt = (unsigned int*)(ws + 5587044);  // 8

    tm_kernel<<<481, 256, 0, stream>>>(in1, in2, w1, w2, w3, tab, Mg, cnt);
    kernel_Y<<<dim3(8, 64), 256, 0, stream>>>(xyz1, xyz2, tab, Mg, partial);
    kernel_redfinal<<<dim3(8, 16), 256, 0, stream>>>(partial, mask, fc3w, fc2w,
                                                     s2, cnt, out);
}